// Round 1
// 680.369 us; speedup vs baseline: 1.0592x; 1.0592x over previous
//
#include <hip/hip_runtime.h>
#include <math.h>

typedef _Float16 f16;
typedef _Float16 half8 __attribute__((ext_vector_type(8)));
typedef _Float16 half4v __attribute__((ext_vector_type(4)));
typedef float f32x4 __attribute__((ext_vector_type(4)));

#define NB 8
#define SEQ 4096
#define QDIM 1280
#define CDIM 1024
#define INNER 1280
#define CTX 85
#define CTXP 96

#define VMCNT(n) asm volatile("s_waitcnt vmcnt(" #n ")" ::: "memory")
#define BAR() do { asm volatile("" ::: "memory"); __builtin_amdgcn_s_barrier(); asm volatile("" ::: "memory"); } while (0)

__device__ __forceinline__ void gload16(const void* g, void* l) {
  __builtin_amdgcn_global_load_lds(
      (const __attribute__((address_space(1))) unsigned int*)g,
      (__attribute__((address_space(3))) unsigned int*)l, 16, 0, 0);
}

// ---------------- cast x fp32 -> f16 (16B stores) ----------------
__global__ void k_cast(const float* __restrict__ x, f16* __restrict__ xh, long n8) {
  long i = blockIdx.x * 256L + threadIdx.x;
  if (i >= n8) return;
  float4 a = ((const float4*)x)[2 * i];
  float4 b = ((const float4*)x)[2 * i + 1];
  half8 o;
  o[0] = (f16)a.x; o[1] = (f16)a.y; o[2] = (f16)a.z; o[3] = (f16)a.w;
  o[4] = (f16)b.x; o[5] = (f16)b.y; o[6] = (f16)b.z; o[7] = (f16)b.w;
  *(half8*)(xh + 8 * i) = o;
}

// ---------------- cast ctx fp32 -> f16, zero-padded to [8][96][1024] ----------------
__global__ void k_castctx(const float* __restrict__ ctx, f16* __restrict__ ctxh) {
  int id = blockIdx.x * 256 + threadIdx.x;  // 8*96*128
  int b = id / (96 * 128);
  int rem = id % (96 * 128);
  int j = rem >> 7;
  int kc = (rem & 127) * 8;
  half8 o = {};
  if (j < CTX) {
    const float* p = ctx + ((long)b * CTX + j) * CDIM + kc;
    float4 a = *(const float4*)p;
    float4 c = *(const float4*)(p + 4);
    o[0] = (f16)a.x; o[1] = (f16)a.y; o[2] = (f16)a.z; o[3] = (f16)a.w;
    o[4] = (f16)c.x; o[5] = (f16)c.y; o[6] = (f16)c.z; o[7] = (f16)c.w;
  }
  *(half8*)(ctxh + (long)id * 8) = o;
}

// ---------------- transpose W [K][Nn] fp32 -> [Nn][K] f16, 64x64 tiles ----------------
__global__ __launch_bounds__(256) void k_transpose(const float* __restrict__ in,
                                                   f16* __restrict__ out, int K, int Nn) {
  __shared__ __attribute__((aligned(16))) f16 T[64][72];
  int n0 = blockIdx.x * 64, k0 = blockIdx.y * 64;
  int t = threadIdx.x;
  int kr = t >> 4, nc = (t & 15) * 4;
  for (int i = 0; i < 4; i++) {
    int k = kr + i * 16;
    float4 v = *(const float4*)&in[(long)(k0 + k) * Nn + n0 + nc];
    T[nc + 0][k] = (f16)v.x;
    T[nc + 1][k] = (f16)v.y;
    T[nc + 2][k] = (f16)v.z;
    T[nc + 3][k] = (f16)v.w;
  }
  __syncthreads();
  for (int i = 0; i < 2; i++) {
    int slot = t + i * 256;
    int n = slot >> 3, ch = (slot & 7) * 8;
    *(half8*)&out[(long)(n0 + n) * K + k0 + ch] = *(half8*)&T[n][ch];
  }
}

// ---------------- fg mask: exact integer bicubic-!=0 ----------------
__global__ void k_fg(const int* __restrict__ mask, unsigned char* __restrict__ fg) {
  int id = blockIdx.x * 256 + threadIdx.x;  // 8*4096
  int b = id >> 12, o = (id >> 6) & 63, p = id & 63;
  const int* mb = mask + (long)b * 65536;
  const int w[4] = {-3, 19, 19, -3};
  int s = 0;
  for (int dh = 0; dh < 4; dh++) {
    const int* row = mb + (4 * o + dh) * 256 + 4 * p;
    int rs = -3 * row[0] + 19 * row[1] + 19 * row[2] - 3 * row[3];
    s += w[dh] * rs;
  }
  fg[id] = (s != 0) ? 1 : 0;
}

// ---------------- K/V projection: register-only skinny GEMM ----------------
__global__ __launch_bounds__(256) void k_kvproj(const f16* __restrict__ ctxh,
    const f16* __restrict__ WkT, const f16* __restrict__ WvT,
    f16* __restrict__ kpad, f16* __restrict__ vT) {
  int b = blockIdx.y, kv = blockIdx.z;
  const f16* WT = kv ? WvT : WkT;
  int w = threadIdx.x >> 6, lane = threadIdx.x & 63;
  int ln = lane & 15, qd = lane >> 4;
  int n0 = (blockIdx.x * 4 + w) * 16;
  const f16* arow = ctxh + ((long)b * CTXP + ln) * CDIM + qd * 8;
  const f16* brow = WT + (long)(n0 + ln) * CDIM + qd * 8;
  f32x4 acc[6] = {};
#pragma unroll 4
  for (int k0 = 0; k0 < CDIM; k0 += 32) {
    half8 bf = *(const half8*)(brow + k0);
#pragma unroll
    for (int mt = 0; mt < 6; mt++) {
      half8 af = *(const half8*)(arow + mt * 16 * CDIM + k0);
      acc[mt] = __builtin_amdgcn_mfma_f32_16x16x32_f16(af, bf, acc[mt], 0, 0, 0);
    }
  }
  if (kv == 0) {
    for (int mt = 0; mt < 6; mt++)
      for (int r = 0; r < 4; r++)
        kpad[((long)b * CTXP + mt * 16 + qd * 4 + r) * INNER + n0 + ln] = (f16)acc[mt][r];
  } else {
    for (int mt = 0; mt < 6; mt++) {
      half4v pv;
      for (int r = 0; r < 4; r++) pv[r] = (f16)acc[mt][r];
      *(half4v*)&vT[((long)b * INNER + n0 + ln) * CTXP + mt * 16 + qd * 4] = pv;
    }
  }
}

// ---------------- legacy 128x128 GEMM (fallback path) ----------------
template <int OUT_F32>
__global__ __launch_bounds__(256) void k_gemm(const f16* __restrict__ A,
    const f16* __restrict__ Bt, const float* __restrict__ bias,
    f16* __restrict__ outh, float* __restrict__ outf, int K) {
  __shared__ __attribute__((aligned(16))) f16 Alds[128 * 64];
  __shared__ __attribute__((aligned(16))) f16 Blds[128 * 64];
  int tid = threadIdx.x, lane = tid & 63, w = tid >> 6;
  int wr = w >> 1, wc = w & 1;
  int ln = lane & 15, qd = lane >> 4;
  long m0 = (long)blockIdx.x * 128;
  int n0 = blockIdx.y * 128;
  int srow = lane >> 3;
  int schunk = lane & 7;
  f32x4 acc[4][4] = {};
  for (int k0 = 0; k0 < K; k0 += 64) {
#pragma unroll
    for (int i = 0; i < 4; i++) {
      int row = w * 32 + i * 8 + srow;
      int ca = (schunk ^ (row & 7)) * 8;
      gload16(&A[(m0 + row) * K + k0 + ca], &Alds[w * 2048 + i * 512]);
      gload16(&Bt[(long)(n0 + row) * K + k0 + ca], &Blds[w * 2048 + i * 512]);
    }
    __syncthreads();
#pragma unroll
    for (int s = 0; s < 2; s++) {
      half8 af[4], bf[4];
#pragma unroll
      for (int mt = 0; mt < 4; mt++) {
        int row = wr * 64 + mt * 16 + ln;
        af[mt] = *(half8*)&Alds[row * 64 + (((s * 4 + qd) ^ (row & 7)) * 8)];
      }
#pragma unroll
      for (int nt = 0; nt < 4; nt++) {
        int row = wc * 64 + nt * 16 + ln;
        bf[nt] = *(half8*)&Blds[row * 64 + (((s * 4 + qd) ^ (row & 7)) * 8)];
      }
#pragma unroll
      for (int mt = 0; mt < 4; mt++)
#pragma unroll
        for (int nt = 0; nt < 4; nt++)
          acc[mt][nt] = __builtin_amdgcn_mfma_f32_16x16x32_f16(af[mt], bf[nt], acc[mt][nt], 0, 0, 0);
    }
    __syncthreads();
  }
  for (int mt = 0; mt < 4; mt++) {
    long mrow = m0 + wr * 64 + mt * 16 + qd * 4;
    for (int nt = 0; nt < 4; nt++) {
      int n = n0 + wc * 64 + nt * 16 + ln;
      float bv = OUT_F32 ? bias[n] : 0.f;
      for (int r = 0; r < 4; r++) {
        if (OUT_F32) outf[(mrow + r) * INNER + n] = acc[mt][nt][r] + bv;
        else         outh[(mrow + r) * INNER + n] = (f16)acc[mt][nt][r];
      }
    }
  }
}

// ---------------- 256x256 4-phase counted-vmcnt GEMM (m201-style template) ----------------
// 512 threads = 8 waves (2M x 4N), per-wave 128x64 output, BK=64, dbuf LDS 128 KiB.
// LDS rows are 64 halfs = 8x16B chunks; chunk c of row r stored at slot (c ^ (r&7))
// via pre-swizzled global source (global_load_lds writes linearly). Main-loop waits
// are counted (vmcnt(2)), never a full drain.
__device__ __forceinline__ void stage2(const f16* __restrict__ g, int ldK,
                                       f16* lds, int tid, int c0) {
#pragma unroll
  for (int c = c0; c < c0 + 2; ++c) {
    int row = c * 64 + (tid >> 3);
    int sc = (tid & 7) ^ (row & 7);
    gload16(g + (long)row * ldK + sc * 8, lds + c * 4096 + (tid >> 6) * 512);
  }
}

template <int OUT_F32>
__global__ __launch_bounds__(512, 2) void k_gemm256(const f16* __restrict__ A,
    const f16* __restrict__ Bt, const float* __restrict__ bias,
    f16* __restrict__ outh, float* __restrict__ outf, int K) {
  extern __shared__ __attribute__((aligned(16))) f16 smem[];
  f16* As0 = smem;             // [256][64] halfs, 32 KiB
  f16* As1 = smem + 16384;
  f16* Bs0 = smem + 32768;
  f16* Bs1 = smem + 49152;
  const int NT = K >> 6;       // 20
  int tid = threadIdx.x, lane = tid & 63, w = tid >> 6;
  int wr = w >> 2, wc = w & 3;
  int ln = lane & 15, qd = lane >> 4;
  int wrb = wr * 128, wcb = wc * 64;
  // bijective XCD swizzle (gridDim.x % 8 == 0); consecutive swz share a B-panel
  int cpx = gridDim.x >> 3;
  int swz = (blockIdx.x & 7) * cpx + (blockIdx.x >> 3);
  int mtile = swz & 127, ntile = swz >> 7;   // 128 m-tiles x 5 n-tiles
  long m0 = (long)mtile * 256;
  int n0 = ntile * 256;
  const f16* Ab = A + m0 * K;
  const f16* Bb = Bt + (long)n0 * K;

  half8 af[4][2], bf[2][2];
  f32x4 acc[8][4] = {};

  auto rdA = [&](const f16* Ac, int mh) {
#pragma unroll
    for (int mt = 0; mt < 4; ++mt) {
      int R = wrb + mh * 64 + mt * 16 + ln;
      const f16* rp = Ac + R * 64;
      int r7 = (R & 7) << 3;
      af[mt][0] = *(const half8*)(rp + ((qd << 3) ^ r7));
      af[mt][1] = *(const half8*)(rp + (((4 + qd) << 3) ^ r7));
    }
  };
  auto rdB = [&](const f16* Bc, int nh) {
#pragma unroll
    for (int nt = 0; nt < 2; ++nt) {
      int R = wcb + nh * 32 + nt * 16 + ln;
      const f16* rp = Bc + R * 64;
      int r7 = (R & 7) << 3;
      bf[nt][0] = *(const half8*)(rp + ((qd << 3) ^ r7));
      bf[nt][1] = *(const half8*)(rp + (((4 + qd) << 3) ^ r7));
    }
  };
  auto mm = [&](int mh, int nh) {
    __builtin_amdgcn_s_setprio(1);
#pragma unroll
    for (int ks = 0; ks < 2; ++ks)
#pragma unroll
      for (int mt = 0; mt < 4; ++mt)
#pragma unroll
        for (int nt = 0; nt < 2; ++nt)
          acc[mh * 4 + mt][nh * 2 + nt] = __builtin_amdgcn_mfma_f32_16x16x32_f16(
              af[mt][ks], bf[nt][ks], acc[mh * 4 + mt][nh * 2 + nt], 0, 0, 0);
    __builtin_amdgcn_s_setprio(0);
  };

  // prologue: tile0 fully staged; tile1 A.c01 left in flight (matches steady state)
  stage2(Ab, K, As0, tid, 0); stage2(Ab, K, As0, tid, 2);
  stage2(Bb, K, Bs0, tid, 0); stage2(Bb, K, Bs0, tid, 2);
  if (NT > 1) { stage2(Ab + 64, K, As1, tid, 0); VMCNT(2); } else { VMCNT(0); }
  BAR();

  // 4 phases/K-tile, quadrant order (0,0)(0,1)(1,1)(1,0); 2 barriers/phase.
  // Stage schedule (safe by region-last-read analysis):
  //   ph0: A(kt+1).c23 + B(kt+1).c01  (other buffer fully free since prev boundary)
  //   ph1: B(kt+1).c23
  //   ph3: A(kt+2).c01 into CURRENT buffer's A region (A-reads done at ph2-end barrier)
  // boundary wait: vmcnt(2) -> everything except A(kt+2).c01 complete.
#define TILE256(KT, AC, BC, AN, BN_) do {                                        \
    rdA(AC, 0); rdB(BC, 0);                                                      \
    if ((KT) + 1 < NT) { stage2(Ab + ((KT) + 1) * 64, K, AN, tid, 2);            \
                         stage2(Bb + ((KT) + 1) * 64, K, BN_, tid, 0); }         \
    BAR(); mm(0, 0); BAR();                                                      \
    rdB(BC, 1);                                                                  \
    if ((KT) + 1 < NT) stage2(Bb + ((KT) + 1) * 64, K, BN_, tid, 2);             \
    BAR(); mm(0, 1); BAR();                                                      \
    rdA(AC, 1);                                                                  \
    BAR(); mm(1, 1); BAR();                                                      \
    rdB(BC, 0);                                                                  \
    if ((KT) + 2 < NT) stage2(Ab + ((KT) + 2) * 64, K, AC, tid, 0);              \
    BAR(); mm(1, 0);                                                             \
    if ((KT) + 2 < NT) { VMCNT(2); } else if ((KT) + 1 < NT) { VMCNT(0); }       \
    BAR();                                                                       \
  } while (0)

#pragma unroll 1
  for (int kt = 0; kt < NT; kt += 2) {
    TILE256(kt, As0, Bs0, As1, Bs1);
    TILE256(kt + 1, As1, Bs1, As0, Bs0);
  }
#undef TILE256

  // epilogue: direct stores from accumulators
#pragma unroll
  for (int mt = 0; mt < 8; ++mt) {
    long rb = m0 + wrb + mt * 16 + qd * 4;
#pragma unroll
    for (int nt = 0; nt < 4; ++nt) {
      int col = n0 + wcb + nt * 16 + ln;
      if (OUT_F32) {
        float bv = bias[col];
#pragma unroll
        for (int r = 0; r < 4; ++r)
          outf[(rb + r) * INNER + col] = acc[mt][nt][r] + bv;
      } else {
#pragma unroll
        for (int r = 0; r < 4; ++r)
          outh[(rb + r) * INNER + col] = (f16)acc[mt][nt][r];
      }
    }
  }
}

// ---------------- fused masked attention ----------------
__global__ __launch_bounds__(256) void k_attn(const f16* __restrict__ q,
    const f16* __restrict__ kpad, const f16* __restrict__ vT,
    const unsigned char* __restrict__ fg, f16* __restrict__ ao) {
  int mb = blockIdx.x;
  int h = blockIdx.y;
  int b = blockIdx.z;
  __shared__ __attribute__((aligned(16))) f16 Klds[CTXP][72];
  __shared__ __attribute__((aligned(16))) f16 Vlds[64][104];
  __shared__ __attribute__((aligned(16))) f16 Plds[4][16][104];
  int tid = threadIdx.x, lane = tid & 63, w = tid >> 6;
  int ln = lane & 15, qd = lane >> 4;

  for (int c = tid; c < CTXP * 8; c += 256) {
    int j = c >> 3, kc = (c & 7) * 8;
    *(half8*)&Klds[j][kc] = *(const half8*)&kpad[((long)b * CTXP + j) * INNER + h * 64 + kc];
  }
  for (int c = tid; c < 64 * 12; c += 256) {
    int d = c / 12, jc = (c % 12) * 8;
    *(half8*)&Vlds[d][jc] = *(const half8*)&vT[((long)b * INNER + h * 64 + d) * CTXP + jc];
  }
  __syncthreads();

  long mg = (long)b * SEQ + mb * 64 + w * 16 + ln;
  half8 qf[2];
  for (int s = 0; s < 2; s++)
    qf[s] = *(const half8*)&q[mg * INNER + h * 64 + s * 32 + qd * 8];

  f32x4 sacc[6] = {};
  for (int s = 0; s < 2; s++)
    for (int nt = 0; nt < 6; nt++) {
      half8 bf = *(half8*)&Klds[nt * 16 + ln][s * 32 + qd * 8];
      sacc[nt] = __builtin_amdgcn_mfma_f32_16x16x32_f16(qf[s], bf, sacc[nt], 0, 0, 0);
    }

  unsigned int fgw = *(const unsigned int*)&fg[(long)b * SEQ + mb * 64 + w * 16 + qd * 4];
  const float scale = 0.125f;
  for (int r = 0; r < 4; r++) {
    bool f = ((fgw >> (8 * r)) & 0xff) != 0;
    float vals[6];
    bool oks[6];
    float mx = -1e30f;
    for (int nt = 0; nt < 6; nt++) {
      int j = nt * 16 + ln;
      bool ok = (j < 77) || (j < 81 ? f : (j < 85 ? !f : false));
      float v = sacc[nt][r] * scale;
      vals[nt] = v; oks[nt] = ok;
      if (ok) mx = fmaxf(mx, v);
    }
    for (int d = 1; d < 16; d <<= 1) mx = fmaxf(mx, __shfl_xor(mx, d, 64));
    float sum = 0.f, p[6];
    for (int nt = 0; nt < 6; nt++) {
      p[nt] = oks[nt] ? __expf(vals[nt] - mx) : 0.f;
      sum += p[nt];
    }
    for (int d = 1; d < 16; d <<= 1) sum += __shfl_xor(sum, d, 64);
    float inv = 1.f / sum;
    for (int nt = 0; nt < 6; nt++)
      Plds[w][qd * 4 + r][nt * 16 + ln] = (f16)(p[nt] * inv);
  }
  __syncthreads();

  f32x4 oacc[4] = {};
  for (int ks = 0; ks < 3; ks++) {
    half8 pf = *(half8*)&Plds[w][ln][ks * 32 + qd * 8];
    for (int ntd = 0; ntd < 4; ntd++) {
      half8 vf = *(half8*)&Vlds[ntd * 16 + ln][ks * 32 + qd * 8];
      oacc[ntd] = __builtin_amdgcn_mfma_f32_16x16x32_f16(pf, vf, oacc[ntd], 0, 0, 0);
    }
  }
  for (int ntd = 0; ntd < 4; ntd++)
    for (int r = 0; r < 4; r++)
      Plds[w][qd * 4 + r][ntd * 16 + ln] = (f16)oacc[ntd][r];
  __syncthreads();
  long rowbase = (long)b * SEQ + mb * 64 + w * 16;
  for (int i = 0; i < 2; i++) {
    int slot = lane + i * 64;
    int rrow = slot >> 3, ch = (slot & 7) * 8;
    *(half8*)&ao[(rowbase + rrow) * INNER + h * 64 + ch] = *(half8*)&Plds[w][rrow][ch];
  }
}

extern "C" void kernel_launch(void* const* d_in, const int* in_sizes, int n_in,
                              void* d_out, int out_size, void* d_ws, size_t ws_size,
                              hipStream_t stream) {
  const float* x   = (const float*)d_in[0];
  const float* ctx = (const float*)d_in[1];
  const float* Wq  = (const float*)d_in[2];
  const float* Wk  = (const float*)d_in[3];
  const float* Wv  = (const float*)d_in[4];
  const float* Wo  = (const float*)d_in[5];
  const float* bo  = (const float*)d_in[6];
  const int*  mask = (const int*)d_in[7];
  float* out = (float*)d_out;

  char* ws = (char*)d_ws;
  size_t off = 0;
  f16* xh  = (f16*)(ws + off); off += 83886080;   // 8*4096*1280 f16
  f16* q   = (f16*)(ws + off); off += 83886080;
  f16* ao  = (f16*)(ws + off); off += 83886080;
  f16* WqT = (f16*)(ws + off); off += 3276800;
  f16* WoT = (f16*)(ws + off); off += 3276800;
  f16* WkT = (f16*)(ws + off); off += 2621440;
  f16* WvT = (f16*)(ws + off); off += 2621440;
  f16* kpad= (f16*)(ws + off); off += 1966080;    // [8][96][1280]
  f16* vT  = (f16*)(ws + off); off += 1966080;    // [8][1280][96]
  f16* ctxh= (f16*)(ws + off); off += 1572864;    // [8][96][1024] zero-padded
  unsigned char* fg = (unsigned char*)(ws + off); off += 32768;
  if (ws_size < off) return;

  // one-time: allow 128 KiB dynamic LDS for the 256^2 GEMM; fall back if refused
  static int g_use256 = -1;
  if (g_use256 < 0) {
    auto* f0 = k_gemm256<0>;
    auto* f1 = k_gemm256<1>;
    hipError_t e0 = hipFuncSetAttribute(reinterpret_cast<const void*>(f0),
                                        hipFuncAttributeMaxDynamicSharedMemorySize, 131072);
    hipError_t e1 = hipFuncSetAttribute(reinterpret_cast<const void*>(f1),
                                        hipFuncAttributeMaxDynamicSharedMemorySize, 131072);
    g_use256 = (e0 == hipSuccess && e1 == hipSuccess) ? 1 : 0;
  }

  k_cast<<<20480, 256, 0, stream>>>(x, xh, 5242880);
  k_castctx<<<384, 256, 0, stream>>>(ctx, ctxh);
  k_transpose<<<dim3(1280/64, 1280/64), 256, 0, stream>>>(Wq, WqT, 1280, 1280);
  k_transpose<<<dim3(1280/64, 1024/64), 256, 0, stream>>>(Wk, WkT, 1024, 1280);
  k_transpose<<<dim3(1280/64, 1024/64), 256, 0, stream>>>(Wv, WvT, 1024, 1280);
  k_transpose<<<dim3(1280/64, 1280/64), 256, 0, stream>>>(Wo, WoT, 1280, 1280);
  k_fg<<<128, 256, 0, stream>>>(mask, fg);
  k_kvproj<<<dim3(20, 8, 2), 256, 0, stream>>>(ctxh, WkT, WvT, kpad, vT);
  if (g_use256) {
    k_gemm256<0><<<640, 512, 131072, stream>>>(xh, WqT, nullptr, q, nullptr, 1280);
  } else {
    k_gemm<0><<<dim3(256, 10), 256, 0, stream>>>(xh, WqT, nullptr, q, nullptr, 1280);
  }
  k_attn<<<dim3(64, 20, 8), 256, 0, stream>>>(q, kpad, vT, fg, ao);
  if (g_use256) {
    k_gemm256<1><<<640, 512, 131072, stream>>>(ao, WoT, bo, nullptr, out, 1280);
  } else {
    k_gemm<1><<<dim3(256, 10), 256, 0, stream>>>(ao, WoT, bo, nullptr, out, 1280);
  }
}